// Round 16
// baseline (447.512 us; speedup 1.0000x reference)
//
#include <hip/hip_runtime.h>

// Problem constants (SpeakerAwareCTC): B=16, T=1000, D=512, V=5000, U=64, S=2U+1=129
#define NB 16
#define NT 1000
#define ND 512
#define NV 5000
#define NVP 5120          // WT padded rows (zeros beyond 5000)
#define NU 64
#define NLL 66            // ll row stride (u-major rows, 65 used)
#define NM (NB * NT)      // 16000 flattened rows
#define NCH 40            // N-chunks of 128 cols

typedef short short8v __attribute__((ext_vector_type(8)));
typedef float float4v __attribute__((ext_vector_type(4)));

#define NEGINF (-__builtin_inff())
#define SENTL  (-1.0e30f)   // finite "-inf"
#define LOG2E 1.4426950408889634f
#define LN2F  0.6931471805599453f
// reference sentinel: -2001 + logf(expf(1)-1) = -2000.4586751f (natural), base-2:
#define SENT2 (-2000.4586751f * LOG2E)

__device__ __forceinline__ float fexp2(float x) { return __builtin_amdgcn_exp2f(x); }
__device__ __forceinline__ float flog2(float x) { return __builtin_amdgcn_logf(x); }

__device__ __forceinline__ float dpp_shl1(float x) {  // lane i <- lane i+1
  int xi = __builtin_bit_cast(int, x);
  int r = __builtin_amdgcn_update_dpp(xi, xi, 0x130, 0xf, 0xf, false);
  return __builtin_bit_cast(float, r);
}
__device__ __forceinline__ float dpp_shr1(float x) {  // lane i <- lane i-1
  int xi = __builtin_bit_cast(int, x);
  int r = __builtin_amdgcn_update_dpp(xi, xi, 0x138, 0xf, 0xf, false);
  return __builtin_bit_cast(float, r);
}

__device__ __forceinline__ short f2bf(float x) {
  unsigned int u = __builtin_bit_cast(unsigned int, x);
  unsigned int r = (u + 0x7fffu + ((u >> 16) & 1u)) >> 16;
  return (short)(unsigned short)r;
}
__device__ __forceinline__ float bf2f(short h) {
  unsigned int u = ((unsigned int)(unsigned short)h) << 16;
  return __builtin_bit_cast(float, u);
}

__device__ __forceinline__ void g2lds16(const short* g, short* l) {
  __builtin_amdgcn_global_load_lds(
      (const __attribute__((address_space(1))) void*)g,
      (__attribute__((address_space(3))) void*)l, 16, 0, 0);
}

__device__ __forceinline__ float lae2s(float a, float b) {
  float m = fmaxf(a, b);
  return m + flog2(fexp2(a - m) + fexp2(b - m));
}
__device__ __forceinline__ float lae3s(float a, float b, float c) {
  float m = fmaxf(fmaxf(a, b), c);
  return m + flog2(fexp2(a - m) + fexp2(b - m) + fexp2(c - m));
}
// faithful log_substraction_exp (normalized domain, finite sentinels)
__device__ __forceinline__ float lsub2(float a, float b) {
  if (b < -1.0e29f) return (a < -1.0e29f) ? SENTL : a;
  float tmp = b + flog2(fexp2(a - b) - 1.0f);
  if (__builtin_isinf(tmp)) tmp = SENT2;
  return tmp;   // NaN (a<b rounding) passes through -> masked in loss
}

// ------ kernel 1: fused converts: hs->bf16 swizzled | W->WT/WTlo ----------
__global__ __launch_bounds__(256) void k_cvt(const float* __restrict__ hs,
                                             const float* __restrict__ W,
                                             short* __restrict__ hsb,
                                             short* __restrict__ WT,
                                             short* __restrict__ WTlo,
                                             float* __restrict__ outv) {
  __shared__ short tileH[64 * 72];
  __shared__ short tileL[64 * 72];
  if (blockIdx.x < 4000) {
    if (blockIdx.x == 0 && threadIdx.x == 0) outv[0] = 0.0f;
    size_t i = (size_t)blockIdx.x * 256 + threadIdx.x;
    const float4* p = (const float4*)hs + i * 2;
    float4 v0 = p[0], v1 = p[1];
    short8v r;
    r[0] = f2bf(v0.x); r[1] = f2bf(v0.y); r[2] = f2bf(v0.z); r[3] = f2bf(v0.w);
    r[4] = f2bf(v1.x); r[5] = f2bf(v1.y); r[6] = f2bf(v1.z); r[7] = f2bf(v1.w);
    int row = (int)(i >> 6);
    int g = (int)(i & 63);
    int gs = (g & ~7) | ((g & 7) ^ (row & 7));
    *(short8v*)(hsb + (size_t)row * ND + gs * 8) = r;
    return;
  }
  int bx = blockIdx.x - 4000;
  int n0 = (bx % 80) * 64, k0 = (bx / 80) * 64;
  int tid = threadIdx.x;
  int kr = tid >> 2, part = tid & 3;
  const float* src = W + (size_t)(k0 + kr) * NV + n0 + part * 16;
#pragma unroll
  for (int jj = 0; jj < 4; ++jj) {
    int c = n0 + part * 16 + jj * 4;
    float4 v;
    if (c + 3 < NV) {
      v = *(const float4*)(src + jj * 4);
    } else {
      v.x = (c + 0 < NV) ? src[jj * 4 + 0] : 0.f;
      v.y = (c + 1 < NV) ? src[jj * 4 + 1] : 0.f;
      v.z = (c + 2 < NV) ? src[jj * 4 + 2] : 0.f;
      v.w = (c + 3 < NV) ? src[jj * 4 + 3] : 0.f;
    }
    int base = kr * 72 + part * 16 + jj * 4;
    float vv[4] = {v.x, v.y, v.z, v.w};
#pragma unroll
    for (int q = 0; q < 4; ++q) {
      short h = f2bf(vv[q]);
      tileH[base + q] = h;
      tileL[base + q] = f2bf(vv[q] - bf2f(h));
    }
  }
  __syncthreads();
  int n = tid & 63, kq = tid >> 6;
  int nn = n0 + n;
  if (nn < NVP) {
#pragma unroll
    for (int half = 0; half < 2; ++half) {
      short8v vh, vl;
#pragma unroll
      for (int jj = 0; jj < 8; ++jj) {
        vh[jj] = tileH[(kq * 16 + half * 8 + jj) * 72 + n];
        vl[jj] = tileL[(kq * 16 + half * 8 + jj) * 72 + n];
      }
      int g = (k0 >> 3) + kq * 2 + half;
      int gs = (g & ~7) | ((g & 7) ^ (nn & 7));
      *(short8v*)(WT + (size_t)nn * ND + gs * 8) = vh;
      *(short8v*)(WTlo + (size_t)nn * ND + gs * 8) = vl;
    }
  }
}

// -------- kernel 2: ll[b][u][t] = hs . W[:,lab(u)] + bias (direct WT read) -
__global__ __launch_bounds__(256) void k_labg(const short* __restrict__ hsb,
                                              const short* __restrict__ WT,
                                              const short* __restrict__ WTlo,
                                              const int* __restrict__ ys,
                                              const float* __restrict__ bias,
                                              float* __restrict__ ll) {
  __shared__ short As[128 * 64];
  __shared__ short Bh[128 * 64];
  __shared__ short Bl[128 * 64];

  int mt = blockIdx.x, b = blockIdx.y;
  int t0 = mt * 128;
  int tid = threadIdx.x;
  int lane = tid & 63, wave = tid >> 6;
  int wm = wave >> 1, wn = wave & 1;
  int lrow = lane & 15, lkhi = lane >> 4;

  const short* gaBase = hsb + (size_t)(b * NT + t0 + wave * 32 + (lane >> 3)) * ND + (lane & 7) * 8;

  int labv[4], xorv[4];
#pragma unroll
  for (int i = 0; i < 4; ++i) {
    int r = wave * 32 + (lane >> 3) + i * 8;
    int lab = (r == 0) ? 0 : ((r <= NU) ? ys[b * NU + r - 1] : NV);  // row NV = zeros
    labv[i] = lab;
    xorv[i] = ((lane & 7) ^ (r & 7) ^ (lab & 7)) * 8;
  }

  float4v acc[4][4];
#pragma unroll
  for (int m = 0; m < 4; ++m)
#pragma unroll
    for (int n = 0; n < 4; ++n)
#pragma unroll
      for (int j = 0; j < 4; ++j) acc[m][n][j] = 0.f;

  for (int s = 0; s < 8; ++s) {
    int k0 = s * 64;
#pragma unroll
    for (int i = 0; i < 4; ++i) {
      g2lds16(gaBase + (size_t)(i * 8) * ND + k0, &As[(wave * 32 + i * 8) * 64]);
      g2lds16(WT + (size_t)labv[i] * ND + k0 + xorv[i], &Bh[(wave * 32 + i * 8) * 64]);
      g2lds16(WTlo + (size_t)labv[i] * ND + k0 + xorv[i], &Bl[(wave * 32 + i * 8) * 64]);
    }
    __syncthreads();
#pragma unroll
    for (int kk = 0; kk < 2; ++kk) {
      short8v av[4], bhv[4], blv2[4];
#pragma unroll
      for (int m = 0; m < 4; ++m) {
        int r = wm * 64 + m * 16 + lrow;
        int col = (kk * 32 + lkhi * 8) ^ ((r & 7) << 3);
        av[m] = *(const short8v*)&As[r * 64 + col];
      }
#pragma unroll
      for (int n = 0; n < 4; ++n) {
        int r = wn * 64 + n * 16 + lrow;
        int col = (kk * 32 + lkhi * 8) ^ ((r & 7) << 3);
        bhv[n] = *(const short8v*)&Bh[r * 64 + col];
        blv2[n] = *(const short8v*)&Bl[r * 64 + col];
      }
#pragma unroll
      for (int m = 0; m < 4; ++m)
#pragma unroll
        for (int n = 0; n < 4; ++n) {
          acc[m][n] = __builtin_amdgcn_mfma_f32_16x16x32_bf16(av[m], bhv[n], acc[m][n], 0, 0, 0);
          acc[m][n] = __builtin_amdgcn_mfma_f32_16x16x32_bf16(av[m], blv2[n], acc[m][n], 0, 0, 0);
        }
    }
    __syncthreads();
  }

  float bu[4]; bool uval[4];
#pragma unroll
  for (int n = 0; n < 4; ++n) {
    int u = wn * 64 + n * 16 + lrow;
    uval[n] = u < NU + 1;
    int lab = (u == 0) ? 0 : (uval[n] ? ys[b * NU + u - 1] : 0);
    bu[n] = uval[n] ? bias[lab] : 0.f;
  }
#pragma unroll
  for (int m = 0; m < 4; ++m)
#pragma unroll
    for (int j = 0; j < 4; ++j) {
      int trow = t0 + wm * 64 + m * 16 + lkhi * 4 + j;
      if (trow < NT) {
#pragma unroll
        for (int n = 0; n < 4; ++n) {
          int u = wn * 64 + n * 16 + lrow;
          if (uval[n])
            ll[((size_t)(b * NLL + u)) * NT + trow] = acc[m][n][j] + bu[n];
        }
      }
    }
}

// ---- kernel 3 (k_big): blocks 0..15 = FORWARD trellis (ll-domain);
// blocks 16..5015 = denom GEMM, dbuf + counted vmcnt pipeline. ----
__global__ __launch_bounds__(256) void k_big(const short* __restrict__ hsb,
                                             const short* __restrict__ WT,
                                             const float* __restrict__ bias,
                                             const float* __restrict__ ll,
                                             const int* __restrict__ ys,
                                             float* __restrict__ L,
                                             float* __restrict__ aod) {
  __shared__ short As[2][128 * 64];
  __shared__ short Ws[2][128 * 64];
  __shared__ float mred[128][2];
  __shared__ float sred[128][2];

  int bid = blockIdx.x;
  int tid = threadIdx.x;

  if (bid < NB) {
    // ---------------- forward (alpha_ll, base-2), register chain ------------
    float* pbS = (float*)As;   // pbS[t] = ll_blank[t]*LOG2E
    int b = bid;
    const float* llb = ll + (size_t)b * NLL * NT;
    for (int i = tid; i < NT; i += 256) pbS[i] = llb[i] * LOG2E;
    __syncthreads();
    if (tid >= 64) return;
    int l = tid;
    const float* lrow = llb + (size_t)(1 + l) * NT;

    int lab = ys[b * NU + l];
    int labp = ys[b * NU + ((l >= 1) ? (l - 1) : 0)];
    bool skip = (l >= 1) && (lab != labp);
    float* aodb = aod + (size_t)b * NT * NU;

    float ae = (l == 0) ? pbS[0] : SENTL;
    float ao = (l == 0) ? lrow[0] * LOG2E : SENTL;
    aodb[l] = ao;

    float cl[16], pbr[16];
#pragma unroll
    for (int j = 0; j < 16; ++j) {
      int tt = 1 + j; if (tt > NT - 1) tt = NT - 1;
      cl[j] = lrow[tt];
      pbr[j] = pbS[tt];
    }
    for (int g = 0; g < 63; ++g) {
      float nl[16], pb2[16];
      if (g < 62) {
#pragma unroll
        for (int j = 0; j < 16; ++j) {
          int tt = 17 + g * 16 + j; if (tt > NT - 1) tt = NT - 1;
          nl[j] = lrow[tt];
          pb2[j] = pbS[tt];
        }
      } else {
#pragma unroll
        for (int j = 0; j < 16; ++j) { nl[j] = 0.f; pb2[j] = 0.f; }
      }
#pragma unroll
      for (int j = 0; j < 16; ++j) {
        int t = 1 + g * 16 + j;
        if (t < NT) {
          float pb = pbr[j];
          float pl = cl[j] * LOG2E;
          float po = dpp_shr1(ao); if (l == 0) po = SENTL;
          float aen = pb + lae2s(ae, po);
          float aon = pl + lae3s(ao, ae, skip ? po : SENTL);
          ae = aen; ao = aon;
          aodb[t * NU + l] = ao;
        }
      }
#pragma unroll
      for (int j = 0; j < 16; ++j) { cl[j] = nl[j]; pbr[j] = pb2[j]; }
    }
    return;
  }

  // ---------------- denom GEMM, dbuf + counted vmcnt ----------------
  int lin = bid - NB;
  int o = (lin & 7) * 625 + (lin >> 3);
  int mt, chunk;
  if (o < 4800) {
    int sb = o / 320, w = o % 320;
    mt = sb * 8 + (w & 7);
    chunk = w >> 3;
  } else {
    int w = o - 4800;
    mt = 120 + (w % 5);
    chunk = w / 5;
  }
  int t0 = mt * 128;
  int n0 = chunk * 128;
  int lane = tid & 63, wave = tid >> 6;
  int wm = wave >> 1, wn = wave & 1;
  int lrow = lane & 15, lkhi = lane >> 4;

  const short* gaBase = hsb + (size_t)(t0 + wave * 32 + (lane >> 3)) * ND + (lane & 7) * 8;
  const short* gwBase = WT + (size_t)(n0 + wave * 32 + (lane >> 3)) * ND + (lane & 7) * 8;

  float4v acc[4][4];
#pragma unroll
  for (int m = 0; m < 4; ++m)
#pragma unroll
    for (int n = 0; n < 4; ++n)
#pragma unroll
      for (int j = 0; j < 4; ++j) acc[m][n][j] = 0.f;

  auto stage = [&](int s, int bw) {
    int k0 = s * 64;
#pragma unroll
    for (int i = 0; i < 4; ++i) {
      g2lds16(gaBase + (size_t)(i * 8) * ND + k0, &As[bw][(wave * 32 + i * 8) * 64]);
      g2lds16(gwBase + (size_t)(i * 8) * ND + k0, &Ws[bw][(wave * 32 + i * 8) * 64]);
    }
  };
  auto compute = [&](int bw) {
#pragma unroll
    for (int kk = 0; kk < 2; ++kk) {
      short8v av[4], wv[4];
#pragma unroll
      for (int m = 0; m < 4; ++m) {
        int r = wm * 64 + m * 16 + lrow;
        int col = (kk * 32 + lkhi * 8) ^ ((r & 7) << 3);
        av[m] = *(const short8v*)&As[bw][r * 64 + col];
      }
#pragma unroll
      for (int n = 0; n < 4; ++n) {
        int r = wn * 64 + n * 16 + lrow;
        int col = (kk * 32 + lkhi * 8) ^ ((r & 7) << 3);
        wv[n] = *(const short8v*)&Ws[bw][r * 64 + col];
      }
#pragma unroll
      for (int m = 0; m < 4; ++m)
#pragma unroll
        for (int n = 0; n < 4; ++n)
          acc[m][n] = __builtin_amdgcn_mfma_f32_16x16x32_bf16(av[m], wv[n], acc[m][n], 0, 0, 0);
    }
  };

  stage(0, 0);
  for (int s = 0; s < 8; ++s) {
    if (s < 7) {
      stage(s + 1, (s + 1) & 1);        // issue next-buf loads (stay in flight)
      asm volatile("s_waitcnt vmcnt(8)" ::: "memory");   // cur buf landed
    } else {
      asm volatile("s_waitcnt vmcnt(0)" ::: "memory");
    }
    __builtin_amdgcn_sched_barrier(0);
    __builtin_amdgcn_s_barrier();       // all waves' cur-buf loads done
    compute(s & 1);
    __builtin_amdgcn_sched_barrier(0);
    __builtin_amdgcn_s_barrier();       // readers done before next overwrite issue
  }

  float bcol[4]; bool cval[4];
#pragma unroll
  for (int n = 0; n < 4; ++n) {
    int c = n0 + wn * 64 + n * 16 + lrow;
    cval[n] = c < NV;
    bcol[n] = cval[n] ? bias[c] : 0.f;
  }
#pragma unroll
  for (int m = 0; m < 4; ++m)
#pragma unroll
    for (int j = 0; j < 4; ++j) {
      float mx = NEGINF;
#pragma unroll
      for (int n = 0; n < 4; ++n) {
        float v = cval[n] ? acc[m][n][j] + bcol[n] : NEGINF;
        mx = fmaxf(mx, v);
      }
#pragma unroll
      for (int d = 1; d < 16; d <<= 1) mx = fmaxf(mx, __shfl_xor(mx, d));
      float mxc = fmaxf(mx, -3.0e38f);
      float p = 0.f;
#pragma unroll
      for (int n = 0; n < 4; ++n) {
        float v = cval[n] ? acc[m][n][j] + bcol[n] : NEGINF;
        p += __expf(v - mxc);
      }
#pragma unroll
      for (int d = 1; d < 16; d <<= 1) p += __shfl_xor(p, d);
      if (lrow == 0) {
        int rloc = wm * 64 + m * 16 + lkhi * 4 + j;
        mred[rloc][wn] = mx;
        sred[rloc][wn] = p;
      }
    }
  __syncthreads();
  if (tid < 128) {
    int row = t0 + tid;
    float m0 = mred[tid][0], m1 = mred[tid][1];
    float m = fmaxf(m0, m1);
    float ss = 0.f;
    if (m != NEGINF)
      ss = ((m0 == NEGINF) ? 0.f : sred[tid][0] * __expf(m0 - m))
         + ((m1 == NEGINF) ? 0.f : sred[tid][1] * __expf(m1 - m));
    float Lv = (m == NEGINF || ss <= 0.f) ? NEGINF : m + __logf(ss);
    L[(size_t)chunk * NM + row] = Lv;
  }
}

// ---- kernel 4 (k_dred): combine 40 chunk partials -> dnm[row] -------------
__global__ __launch_bounds__(256) void k_dred(const float* __restrict__ L,
                                              float* __restrict__ dnm) {
  int row = blockIdx.x * 256 + threadIdx.x;
  if (row >= NM) return;
  float m40 = NEGINF;
#pragma unroll
  for (int c = 0; c < NCH; ++c) m40 = fmaxf(m40, L[(size_t)c * NM + row]);
  float s = 0.f;
#pragma unroll
  for (int c = 0; c < NCH; ++c) {
    float Lc = L[(size_t)c * NM + row];
    if (Lc > -1.0e29f) s += __expf(Lc - m40);
  }
  dnm[row] = m40 + __logf(s);
}

// ---- kernel 5 (k_bwd): backward trellis, normalized, register chain.
// 8 batches per block (wave w <-> batch), private LDS slices -> 2 waves/SIMD.
__global__ __launch_bounds__(512) void k_bwd(const float* __restrict__ ll,
                                             const float* __restrict__ dnm,
                                             const int* __restrict__ ys,
                                             float* __restrict__ bp) {
  __shared__ float dnS[8][NT];   // raw den, per-wave slice
  __shared__ float pbS[8][NT];   // (blank - den)*LOG2E
  int wave = threadIdx.x >> 6;
  int l = threadIdx.x & 63;
  int b = blockIdx.x * 8 + wave;
  const float* llb = ll + (size_t)b * NLL * NT;
  const float* dnb = dnm + b * NT;
  for (int t = l; t < NT; t += 64) {
    float d = dnb[t];
    dnS[wave][t] = d;
    pbS[wave][t] = (llb[t] - d) * LOG2E;
  }
  __syncthreads();
  const float* lrow = llb + (size_t)(1 + l) * NT;

  int lab = ys[b * NU + l];
  int labn = ys[b * NU + ((l < NU - 1) ? (l + 1) : l)];
  bool skipn = (l < NU - 1) && (labn != lab);
  float* bpb = bp + (size_t)b * NT * NU;

  float bo = (l == NU - 1) ? 0.0f : SENTL;
  float be = SENTL;
  float b128 = 0.0f;
  bpb[(NT - 1) * NU + l] = bo;

  float cl[16], pbr[16], dnr[16];
#pragma unroll
  for (int j = 0; j < 16; ++j) {
    int tt = NT - 2 - j; if (tt < 0) tt = 0;
    cl[j] = lrow[tt + 1];
    pbr[j] = pbS[wave][tt + 1];
    dnr[j] = dnS[wave][tt + 1];
  }
  for (int g = 0; g < 63; ++g) {
    float nl2[16], pb2[16], dn2[16];
    if (g < 62) {
#pragma unroll
      for (int j = 0; j < 16; ++j) {
        int tt = NT - 2 - 16 * (g + 1) - j; if (tt < 0) tt = 0;
        nl2[j] = lrow[tt + 1];
        pb2[j] = pbS[wave][tt + 1];
        dn2[j] = dnS[wave][tt + 1];
      }
    } else {
#pragma unroll
      for (int j = 0; j < 16; ++j) { nl2[j] = 0.f; pb2[j] = 0.f; dn2[j] = 0.f; }
    }
#pragma unroll
    for (int j = 0; j < 16; ++j) {
      int t = NT - 2 - 16 * g - j;
      if (t >= 0) {
        float pbv = pbr[j];                       // register, off-chain
        float plv = (cl[j] - dnr[j]) * LOG2E;     // register, off-chain
        float me = pbv + be;
        float mo = plv + bo;
        float m128 = pbv + b128;
        float ne = dpp_shl1(me); if (l == NU - 1) ne = m128;
        float no = dpp_shl1(mo); if (l == NU - 1) no = SENTL;
        float ben = lae2s(me, mo);
        float bon = lae3s(mo, ne, skipn ? no : SENTL);
        bpb[t * NU + l] = lsub2(bon, mo);
        be = ben; bo = bon; b128 = m128;
      }
    }
#pragma unroll
    for (int j = 0; j < 16; ++j) { cl[j] = nl2[j]; pbr[j] = pb2[j]; dnr[j] = dn2[j]; }
  }
}

// ---- kernel 6: loss. alpha re-normalized per-t (Dpre prefix from dnm). ----
__global__ __launch_bounds__(512) void k_loss(const float* __restrict__ aod,
                                              const float* __restrict__ bp,
                                              const float* __restrict__ dnm,
                                              const int* __restrict__ hlens,
                                              float* __restrict__ out) {
  __shared__ float denL[NT];
  __shared__ float Dpre[NT];
  __shared__ float choff[64];
  __shared__ float ms[8][64], ss[8][64];
  int b = blockIdx.x, tid = threadIdx.x;
  for (int t = tid; t < NT; t += 512) denL[t] = dnm[b * NT + t];
  __syncthreads();
  if (tid < 64) {
    float s = 0.f;
#pragma unroll
    for (int i = 0; i < 16; ++i) { int t = tid * 16 + i; if (t < NT) s += denL[t]; }
    float v = s;
#pragma unroll
    for (int d = 1; d < 64; d <<= 1) { float u = __shfl_up(v, d); if (tid >= d) v += u; }
    choff[tid] = v - s;
  }
  __syncthreads();
  for (int t = tid; t < NT; t += 512) {
    float s = choff[t >> 4];
    int base = t & ~15;
    for (int i = base; i <= t; ++i) s += denL[i];
    Dpre[t] = s;   // inclusive prefix D(t)
  }
  __syncthreads();
  int w = tid >> 6, l = tid & 63;
  const float* ab = aod + (size_t)b * NT * NU;
  const float* pbp = bp + (size_t)b * NT * NU;
  float m = NEGINF, s = 0.f;
  int t0 = w * 125, t1 = t0 + 125;
  for (int t = t0; t < t1; ++t) {
    float av = ab[t * NU + l];          // alpha_ll (base-2)
    float pv = pbp[t * NU + l];         // bp normalized (base-2)
    float x = av - Dpre[t] * LOG2E + pv;
    if (__builtin_isnan(x) || x < -1.0e29f) continue;
    if (x > m) { s = s * fexp2(m - x) + 1.0f; m = x; }
    else       { s += fexp2(x - m); }
  }
  ms[w][l] = m; ss[w][l] = s;
  __syncthreads();
  if (w == 0) {
    float mm = NEGINF;
#pragma unroll
    for (int i = 0; i < 8; ++i) mm = fmaxf(mm, ms[i][l]);
    float lu;
    if (mm == NEGINF) lu = NEGINF;
    else {
      float st = 0.f;
#pragma unroll
      for (int i = 0; i < 8; ++i)
        st += (ms[i][l] == NEGINF) ? 0.f : ss[i][l] * fexp2(ms[i][l] - mm);
      lu = (mm + flog2(st)) * LN2F;
    }
    bool msk = __builtin_isinf(lu);
    float sv = msk ? 0.f : lu;
    float cv = msk ? 0.f : 1.f;
#pragma unroll
    for (int d = 1; d < 64; d <<= 1) { sv += __shfl_xor(sv, d); cv += __shfl_xor(cv, d); }
    if (l == 0) {
      float lf = sv / cv;
      if (hlens[b] < NU) lf = 0.f;
      atomicAdd(out, -lf * (1.0f / NB));
    }
  }
}

// ---------------------------------------------------------------------------
extern "C" void kernel_launch(void* const* d_in, const int* in_sizes, int n_in,
                              void* d_out, int out_size, void* d_ws, size_t ws_size,
                              hipStream_t stream) {
  const float* hs    = (const float*)d_in[0];
  const int*   hlens = (const int*)d_in[1];
  const int*   ys    = (const int*)d_in[2];
  const float* W     = (const float*)d_in[4];
  const float* bias  = (const float*)d_in[5];
  float* out = (float*)d_out;

  char* ws = (char*)d_ws;
  short* hsb   = (short*)(ws + 0);           // 16,384,000 B  live thru k_big
  short* WT    = (short*)(ws + 16384000);    //  5,242,880 B  live thru k_big
  short* WTlo  = (short*)(ws + 21626880);    //  5,242,880 B  dead after k_labg
  float* aod   = (float*)(ws + 21626880);    //  4,096,000 B  aliases WTlo (k_big writes)
  float* ll    = (float*)(ws + 26869760);    //  4,224,000 B
  float* L     = (float*)(ws + 31093760);    //  2,560,000 B
  float* dnm   = (float*)(ws + 33653760);    //     64,000 B
  float* bpb   = (float*)(ws + 33717760);    //  4,096,000 B  (end 37,813,760)

  k_cvt<<<4640, 256, 0, stream>>>(hs, W, hsb, WT, WTlo, out);
  k_labg<<<dim3(8, 16), 256, 0, stream>>>(hsb, WT, WTlo, ys, bias, ll);
  k_big<<<5016, 256, 0, stream>>>(hsb, WT, bias, ll, ys, L, aod);
  k_dred<<<63, 256, 0, stream>>>(L, dnm);
  k_bwd<<<2, 512, 0, stream>>>(ll, dnm, ys, bpb);
  k_loss<<<16, 512, 0, stream>>>(aod, bpb, dnm, hlens, out);
}

// Round 17
// 384.190 us; speedup vs baseline: 1.1648x; 1.1648x over previous
//
#include <hip/hip_runtime.h>

// Problem constants (SpeakerAwareCTC): B=16, T=1000, D=512, V=5000, U=64, S=2U+1=129
#define NB 16
#define NT 1000
#define ND 512
#define NV 5000
#define NVP 5120          // WT padded rows (zeros beyond 5000)
#define NU 64
#define NLL 66            // ll row stride (u-major rows, 65 used)
#define NM (NB * NT)      // 16000 flattened rows
#define NCH 40            // N-chunks of 128 cols

typedef short short8v __attribute__((ext_vector_type(8)));
typedef float float4v __attribute__((ext_vector_type(4)));

#define NEGINF (-__builtin_inff())
#define SENTL  (-1.0e30f)   // finite "-inf"
#define LOG2E 1.4426950408889634f
#define LN2F  0.6931471805599453f
// reference sentinel: -2001 + logf(expf(1)-1) = -2000.4586751f (natural), base-2:
#define SENT2 (-2000.4586751f * LOG2E)

__device__ __forceinline__ float fexp2(float x) { return __builtin_amdgcn_exp2f(x); }
__device__ __forceinline__ float flog2(float x) { return __builtin_amdgcn_logf(x); }

__device__ __forceinline__ float dpp_shl1(float x) {  // lane i <- lane i+1
  int xi = __builtin_bit_cast(int, x);
  int r = __builtin_amdgcn_update_dpp(xi, xi, 0x130, 0xf, 0xf, false);
  return __builtin_bit_cast(float, r);
}
__device__ __forceinline__ float dpp_shr1(float x) {  // lane i <- lane i-1
  int xi = __builtin_bit_cast(int, x);
  int r = __builtin_amdgcn_update_dpp(xi, xi, 0x138, 0xf, 0xf, false);
  return __builtin_bit_cast(float, r);
}

__device__ __forceinline__ short f2bf(float x) {
  unsigned int u = __builtin_bit_cast(unsigned int, x);
  unsigned int r = (u + 0x7fffu + ((u >> 16) & 1u)) >> 16;
  return (short)(unsigned short)r;
}
__device__ __forceinline__ float bf2f(short h) {
  unsigned int u = ((unsigned int)(unsigned short)h) << 16;
  return __builtin_bit_cast(float, u);
}

__device__ __forceinline__ void g2lds16(const short* g, short* l) {
  __builtin_amdgcn_global_load_lds(
      (const __attribute__((address_space(1))) void*)g,
      (__attribute__((address_space(3))) void*)l, 16, 0, 0);
}

__device__ __forceinline__ float lae2s(float a, float b) {
  float m = fmaxf(a, b);
  return m + flog2(fexp2(a - m) + fexp2(b - m));
}
__device__ __forceinline__ float lae3s(float a, float b, float c) {
  float m = fmaxf(fmaxf(a, b), c);
  return m + flog2(fexp2(a - m) + fexp2(b - m) + fexp2(c - m));
}
// faithful log_substraction_exp (normalized domain, finite sentinels)
__device__ __forceinline__ float lsub2(float a, float b) {
  if (b < -1.0e29f) return (a < -1.0e29f) ? SENTL : a;
  float tmp = b + flog2(fexp2(a - b) - 1.0f);
  if (__builtin_isinf(tmp)) tmp = SENT2;
  return tmp;   // NaN (a<b rounding) passes through -> masked in loss
}

// ------ kernel 1: fused converts: hs->bf16 swizzled | W->WT/WTlo ----------
__global__ __launch_bounds__(256) void k_cvt(const float* __restrict__ hs,
                                             const float* __restrict__ W,
                                             short* __restrict__ hsb,
                                             short* __restrict__ WT,
                                             short* __restrict__ WTlo,
                                             float* __restrict__ outv) {
  __shared__ short tileH[64 * 72];
  __shared__ short tileL[64 * 72];
  if (blockIdx.x < 4000) {
    if (blockIdx.x == 0 && threadIdx.x == 0) outv[0] = 0.0f;
    size_t i = (size_t)blockIdx.x * 256 + threadIdx.x;
    const float4* p = (const float4*)hs + i * 2;
    float4 v0 = p[0], v1 = p[1];
    short8v r;
    r[0] = f2bf(v0.x); r[1] = f2bf(v0.y); r[2] = f2bf(v0.z); r[3] = f2bf(v0.w);
    r[4] = f2bf(v1.x); r[5] = f2bf(v1.y); r[6] = f2bf(v1.z); r[7] = f2bf(v1.w);
    int row = (int)(i >> 6);
    int g = (int)(i & 63);
    int gs = (g & ~7) | ((g & 7) ^ (row & 7));
    *(short8v*)(hsb + (size_t)row * ND + gs * 8) = r;
    return;
  }
  int bx = blockIdx.x - 4000;
  int n0 = (bx % 80) * 64, k0 = (bx / 80) * 64;
  int tid = threadIdx.x;
  int kr = tid >> 2, part = tid & 3;
  const float* src = W + (size_t)(k0 + kr) * NV + n0 + part * 16;
#pragma unroll
  for (int jj = 0; jj < 4; ++jj) {
    int c = n0 + part * 16 + jj * 4;
    float4 v;
    if (c + 3 < NV) {
      v = *(const float4*)(src + jj * 4);
    } else {
      v.x = (c + 0 < NV) ? src[jj * 4 + 0] : 0.f;
      v.y = (c + 1 < NV) ? src[jj * 4 + 1] : 0.f;
      v.z = (c + 2 < NV) ? src[jj * 4 + 2] : 0.f;
      v.w = (c + 3 < NV) ? src[jj * 4 + 3] : 0.f;
    }
    int base = kr * 72 + part * 16 + jj * 4;
    float vv[4] = {v.x, v.y, v.z, v.w};
#pragma unroll
    for (int q = 0; q < 4; ++q) {
      short h = f2bf(vv[q]);
      tileH[base + q] = h;
      tileL[base + q] = f2bf(vv[q] - bf2f(h));
    }
  }
  __syncthreads();
  int n = tid & 63, kq = tid >> 6;
  int nn = n0 + n;
  if (nn < NVP) {
#pragma unroll
    for (int half = 0; half < 2; ++half) {
      short8v vh, vl;
#pragma unroll
      for (int jj = 0; jj < 8; ++jj) {
        vh[jj] = tileH[(kq * 16 + half * 8 + jj) * 72 + n];
        vl[jj] = tileL[(kq * 16 + half * 8 + jj) * 72 + n];
      }
      int g = (k0 >> 3) + kq * 2 + half;
      int gs = (g & ~7) | ((g & 7) ^ (nn & 7));
      *(short8v*)(WT + (size_t)nn * ND + gs * 8) = vh;
      *(short8v*)(WTlo + (size_t)nn * ND + gs * 8) = vl;
    }
  }
}

// -------- kernel 2: ll[b][u][t] = hs . W[:,lab(u)] + bias (direct WT read) -
__global__ __launch_bounds__(256) void k_labg(const short* __restrict__ hsb,
                                              const short* __restrict__ WT,
                                              const short* __restrict__ WTlo,
                                              const int* __restrict__ ys,
                                              const float* __restrict__ bias,
                                              float* __restrict__ ll) {
  __shared__ short As[128 * 64];
  __shared__ short Bh[128 * 64];
  __shared__ short Bl[128 * 64];

  int mt = blockIdx.x, b = blockIdx.y;
  int t0 = mt * 128;
  int tid = threadIdx.x;
  int lane = tid & 63, wave = tid >> 6;
  int wm = wave >> 1, wn = wave & 1;
  int lrow = lane & 15, lkhi = lane >> 4;

  const short* gaBase = hsb + (size_t)(b * NT + t0 + wave * 32 + (lane >> 3)) * ND + (lane & 7) * 8;

  int labv[4], xorv[4];
#pragma unroll
  for (int i = 0; i < 4; ++i) {
    int r = wave * 32 + (lane >> 3) + i * 8;
    int lab = (r == 0) ? 0 : ((r <= NU) ? ys[b * NU + r - 1] : NV);  // row NV = zeros
    labv[i] = lab;
    xorv[i] = ((lane & 7) ^ (r & 7) ^ (lab & 7)) * 8;
  }

  float4v acc[4][4];
#pragma unroll
  for (int m = 0; m < 4; ++m)
#pragma unroll
    for (int n = 0; n < 4; ++n)
#pragma unroll
      for (int j = 0; j < 4; ++j) acc[m][n][j] = 0.f;

  for (int s = 0; s < 8; ++s) {
    int k0 = s * 64;
#pragma unroll
    for (int i = 0; i < 4; ++i) {
      g2lds16(gaBase + (size_t)(i * 8) * ND + k0, &As[(wave * 32 + i * 8) * 64]);
      g2lds16(WT + (size_t)labv[i] * ND + k0 + xorv[i], &Bh[(wave * 32 + i * 8) * 64]);
      g2lds16(WTlo + (size_t)labv[i] * ND + k0 + xorv[i], &Bl[(wave * 32 + i * 8) * 64]);
    }
    __syncthreads();
#pragma unroll
    for (int kk = 0; kk < 2; ++kk) {
      short8v av[4], bhv[4], blv2[4];
#pragma unroll
      for (int m = 0; m < 4; ++m) {
        int r = wm * 64 + m * 16 + lrow;
        int col = (kk * 32 + lkhi * 8) ^ ((r & 7) << 3);
        av[m] = *(const short8v*)&As[r * 64 + col];
      }
#pragma unroll
      for (int n = 0; n < 4; ++n) {
        int r = wn * 64 + n * 16 + lrow;
        int col = (kk * 32 + lkhi * 8) ^ ((r & 7) << 3);
        bhv[n] = *(const short8v*)&Bh[r * 64 + col];
        blv2[n] = *(const short8v*)&Bl[r * 64 + col];
      }
#pragma unroll
      for (int m = 0; m < 4; ++m)
#pragma unroll
        for (int n = 0; n < 4; ++n) {
          acc[m][n] = __builtin_amdgcn_mfma_f32_16x16x32_bf16(av[m], bhv[n], acc[m][n], 0, 0, 0);
          acc[m][n] = __builtin_amdgcn_mfma_f32_16x16x32_bf16(av[m], blv2[n], acc[m][n], 0, 0, 0);
        }
    }
    __syncthreads();
  }

  float bu[4]; bool uval[4];
#pragma unroll
  for (int n = 0; n < 4; ++n) {
    int u = wn * 64 + n * 16 + lrow;
    uval[n] = u < NU + 1;
    int lab = (u == 0) ? 0 : (uval[n] ? ys[b * NU + u - 1] : 0);
    bu[n] = uval[n] ? bias[lab] : 0.f;
  }
#pragma unroll
  for (int m = 0; m < 4; ++m)
#pragma unroll
    for (int j = 0; j < 4; ++j) {
      int trow = t0 + wm * 64 + m * 16 + lkhi * 4 + j;
      if (trow < NT) {
#pragma unroll
        for (int n = 0; n < 4; ++n) {
          int u = wn * 64 + n * 16 + lrow;
          if (uval[n])
            ll[((size_t)(b * NLL + u)) * NT + trow] = acc[m][n][j] + bu[n];
        }
      }
    }
}

// ---- kernel 3 (k_big): blocks 0..15 = FORWARD trellis (ll-domain);
// blocks 16..5015 = denom GEMM, dbuf + counted vmcnt pipeline. ----
__global__ __launch_bounds__(256) void k_big(const short* __restrict__ hsb,
                                             const short* __restrict__ WT,
                                             const float* __restrict__ bias,
                                             const float* __restrict__ ll,
                                             const int* __restrict__ ys,
                                             float* __restrict__ L,
                                             float* __restrict__ aod) {
  __shared__ short As[2][128 * 64];
  __shared__ short Ws[2][128 * 64];
  __shared__ float mred[128][2];
  __shared__ float sred[128][2];

  int bid = blockIdx.x;
  int tid = threadIdx.x;

  if (bid < NB) {
    // ------- forward (alpha_ll, base-2), register chain, float4 windows -----
    float* pbS = (float*)As;   // pbS[t] = ll_blank[t]*LOG2E, padded 1024
    int b = bid;
    const float* llb = ll + (size_t)b * NLL * NT;
    for (int i = tid; i < NT; i += 256) pbS[i] = llb[i] * LOG2E;
    __syncthreads();
    if (tid >= 64) return;
    int l = tid;
    const float* lrow = llb + (size_t)(1 + l) * NT;

    int lab = ys[b * NU + l];
    int labp = ys[b * NU + ((l >= 1) ? (l - 1) : 0)];
    bool skip = (l >= 1) && (lab != labp);
    float* aodb = aod + (size_t)b * NT * NU;

    float ae = (l == 0) ? pbS[0] : SENTL;
    float ao = (l == 0) ? lrow[0] * LOG2E : SENTL;
    aodb[l] = ao;

#define STEPF(T, CLV, PBV)                                         \
    {                                                              \
      float pl_ = (CLV) * LOG2E;                                   \
      float po_ = dpp_shr1(ao); if (l == 0) po_ = SENTL;           \
      float aen_ = (PBV) + lae2s(ae, po_);                         \
      float aon_ = pl_ + lae3s(ao, ae, skip ? po_ : SENTL);        \
      ae = aen_; ao = aon_;                                        \
      aodb[(T) * NU + l] = ao;                                     \
    }

    float4v h4[4], hp4[4], c4[4], p4[4];
#pragma unroll
    for (int q = 0; q < 4; ++q) {
      h4[q] = *(const float4v*)&lrow[q * 4];          // block 0 (idx 0..15)
      hp4[q] = *(const float4v*)&pbS[q * 4];
      c4[q] = *(const float4v*)&lrow[16 + q * 4];     // window m=1
      p4[q] = *(const float4v*)&pbS[16 + q * 4];
    }
    // head t=1..15
#pragma unroll
    for (int j = 0; j < 15; ++j) {
      int e = 1 + j;
      STEPF(1 + j, h4[e >> 2][e & 3], hp4[e >> 2][e & 3]);
    }
    // main windows m=1..61 (t = 16m..16m+15); m=61 prefetches tail block 992
    for (int m = 1; m <= 61; ++m) {
      float4v n4[4], np4[4];
      int nb = (m < 61) ? (m + 1) * 16 : 992;
#pragma unroll
      for (int q = 0; q < 4; ++q) {
        n4[q] = *(const float4v*)&lrow[nb + q * 4];
        np4[q] = *(const float4v*)&pbS[nb + q * 4];
      }
#pragma unroll
      for (int j = 0; j < 16; ++j)
        STEPF(16 * m + j, c4[j >> 2][j & 3], p4[j >> 2][j & 3]);
#pragma unroll
      for (int q = 0; q < 4; ++q) { c4[q] = n4[q]; p4[q] = np4[q]; }
    }
    // tail t=992..999 (block 992 in c4, elems 0..7)
#pragma unroll
    for (int j = 0; j < 8; ++j)
      STEPF(992 + j, c4[j >> 2][j & 3], p4[j >> 2][j & 3]);
#undef STEPF
    return;
  }

  // ---------------- denom GEMM, dbuf + counted vmcnt ----------------
  int lin = bid - NB;
  int o = (lin & 7) * 625 + (lin >> 3);
  int mt, chunk;
  if (o < 4800) {
    int sb = o / 320, w = o % 320;
    mt = sb * 8 + (w & 7);
    chunk = w >> 3;
  } else {
    int w = o - 4800;
    mt = 120 + (w % 5);
    chunk = w / 5;
  }
  int t0 = mt * 128;
  int n0 = chunk * 128;
  int lane = tid & 63, wave = tid >> 6;
  int wm = wave >> 1, wn = wave & 1;
  int lrow = lane & 15, lkhi = lane >> 4;

  const short* gaBase = hsb + (size_t)(t0 + wave * 32 + (lane >> 3)) * ND + (lane & 7) * 8;
  const short* gwBase = WT + (size_t)(n0 + wave * 32 + (lane >> 3)) * ND + (lane & 7) * 8;

  float4v acc[4][4];
#pragma unroll
  for (int m = 0; m < 4; ++m)
#pragma unroll
    for (int n = 0; n < 4; ++n)
#pragma unroll
      for (int j = 0; j < 4; ++j) acc[m][n][j] = 0.f;

  auto stage = [&](int s, int bw) {
    int k0 = s * 64;
#pragma unroll
    for (int i = 0; i < 4; ++i) {
      g2lds16(gaBase + (size_t)(i * 8) * ND + k0, &As[bw][(wave * 32 + i * 8) * 64]);
      g2lds16(gwBase + (size_t)(i * 8) * ND + k0, &Ws[bw][(wave * 32 + i * 8) * 64]);
    }
  };
  auto compute = [&](int bw) {
#pragma unroll
    for (int kk = 0; kk < 2; ++kk) {
      short8v av[4], wv[4];
#pragma unroll
      for (int m = 0; m < 4; ++m) {
        int r = wm * 64 + m * 16 + lrow;
        int col = (kk * 32 + lkhi * 8) ^ ((r & 7) << 3);
        av[m] = *(const short8v*)&As[bw][r * 64 + col];
      }
#pragma unroll
      for (int n = 0; n < 4; ++n) {
        int r = wn * 64 + n * 16 + lrow;
        int col = (kk * 32 + lkhi * 8) ^ ((r & 7) << 3);
        wv[n] = *(const short8v*)&Ws[bw][r * 64 + col];
      }
#pragma unroll
      for (int m = 0; m < 4; ++m)
#pragma unroll
        for (int n = 0; n < 4; ++n)
          acc[m][n] = __builtin_amdgcn_mfma_f32_16x16x32_bf16(av[m], wv[n], acc[m][n], 0, 0, 0);
    }
  };

  stage(0, 0);
  for (int s = 0; s < 8; ++s) {
    if (s < 7) {
      stage(s + 1, (s + 1) & 1);        // issue next-buf loads (stay in flight)
      asm volatile("s_waitcnt vmcnt(8)" ::: "memory");   // cur buf landed
    } else {
      asm volatile("s_waitcnt vmcnt(0)" ::: "memory");
    }
    __builtin_amdgcn_sched_barrier(0);
    __builtin_amdgcn_s_barrier();       // all waves' cur-buf loads done
    compute(s & 1);
    __builtin_amdgcn_sched_barrier(0);
    __builtin_amdgcn_s_barrier();       // readers done before next overwrite issue
  }

  float bcol[4]; bool cval[4];
#pragma unroll
  for (int n = 0; n < 4; ++n) {
    int c = n0 + wn * 64 + n * 16 + lrow;
    cval[n] = c < NV;
    bcol[n] = cval[n] ? bias[c] : 0.f;
  }
#pragma unroll
  for (int m = 0; m < 4; ++m)
#pragma unroll
    for (int j = 0; j < 4; ++j) {
      float mx = NEGINF;
#pragma unroll
      for (int n = 0; n < 4; ++n) {
        float v = cval[n] ? acc[m][n][j] + bcol[n] : NEGINF;
        mx = fmaxf(mx, v);
      }
#pragma unroll
      for (int d = 1; d < 16; d <<= 1) mx = fmaxf(mx, __shfl_xor(mx, d));
      float mxc = fmaxf(mx, -3.0e38f);
      float p = 0.f;
#pragma unroll
      for (int n = 0; n < 4; ++n) {
        float v = cval[n] ? acc[m][n][j] + bcol[n] : NEGINF;
        p += __expf(v - mxc);
      }
#pragma unroll
      for (int d = 1; d < 16; d <<= 1) p += __shfl_xor(p, d);
      if (lrow == 0) {
        int rloc = wm * 64 + m * 16 + lkhi * 4 + j;
        mred[rloc][wn] = mx;
        sred[rloc][wn] = p;
      }
    }
  __syncthreads();
  if (tid < 128) {
    int row = t0 + tid;
    float m0 = mred[tid][0], m1 = mred[tid][1];
    float m = fmaxf(m0, m1);
    float ss = 0.f;
    if (m != NEGINF)
      ss = ((m0 == NEGINF) ? 0.f : sred[tid][0] * __expf(m0 - m))
         + ((m1 == NEGINF) ? 0.f : sred[tid][1] * __expf(m1 - m));
    float Lv = (m == NEGINF || ss <= 0.f) ? NEGINF : m + __logf(ss);
    L[(size_t)chunk * NM + row] = Lv;
  }
}

// ---- kernel 4 (k_dred): combine 40 chunk partials -> dnm[row] -------------
__global__ __launch_bounds__(256) void k_dred(const float* __restrict__ L,
                                              float* __restrict__ dnm) {
  int row = blockIdx.x * 256 + threadIdx.x;
  if (row >= NM) return;
  float m40 = NEGINF;
#pragma unroll
  for (int c = 0; c < NCH; ++c) m40 = fmaxf(m40, L[(size_t)c * NM + row]);
  float s = 0.f;
#pragma unroll
  for (int c = 0; c < NCH; ++c) {
    float Lc = L[(size_t)c * NM + row];
    if (Lc > -1.0e29f) s += __expf(Lc - m40);
  }
  dnm[row] = m40 + __logf(s);
}

// ---- kernel 5 (k_bwd): backward trellis, normalized, register chain,
// 16 blocks x 1 wave, float4-window prefetch (aligned) ----
__global__ __launch_bounds__(64) void k_bwd(const float* __restrict__ ll,
                                            const float* __restrict__ dnm,
                                            const int* __restrict__ ys,
                                            float* __restrict__ bp) {
  __shared__ float dnS[1024];   // raw den (padded)
  __shared__ float pbS[1024];   // (blank - den)*LOG2E (padded)
  int b = blockIdx.x;
  int l = threadIdx.x;
  const float* llb = ll + (size_t)b * NLL * NT;
  const float* dnb = dnm + b * NT;
  for (int t = l; t < NT; t += 64) {
    float d = dnb[t];
    dnS[t] = d;
    pbS[t] = (llb[t] - d) * LOG2E;
  }
  __syncthreads();
  const float* lrow = llb + (size_t)(1 + l) * NT;

  int lab = ys[b * NU + l];
  int labn = ys[b * NU + ((l < NU - 1) ? (l + 1) : l)];
  bool skipn = (l < NU - 1) && (labn != lab);
  float* bpb = bp + (size_t)b * NT * NU;

  float bo = (l == NU - 1) ? 0.0f : SENTL;
  float be = SENTL;
  float b128 = 0.0f;
  bpb[(NT - 1) * NU + l] = bo;

#define STEPB(T, CLV, PBV, DNV)                                    \
  {                                                                \
    float plv_ = ((CLV) - (DNV)) * LOG2E;                          \
    float me_ = (PBV) + be;                                        \
    float mo_ = plv_ + bo;                                         \
    float m128_ = (PBV) + b128;                                    \
    float ne_ = dpp_shl1(me_); if (l == NU - 1) ne_ = m128_;       \
    float no_ = dpp_shl1(mo_); if (l == NU - 1) no_ = SENTL;       \
    float ben_ = lae2s(me_, mo_);                                  \
    float bon_ = lae3s(mo_, ne_, skipn ? no_ : SENTL);             \
    bpb[(T) * NU + l] = lsub2(bon_, mo_);                          \
    be = ben_; bo = bon_; b128 = m128_;                            \
  }

  float4v h4[4], hp4[4], hd4[4], c4[4], p4[4], d4[4];
#pragma unroll
  for (int q = 0; q < 4; ++q) {
    h4[q] = *(const float4v*)&lrow[992 + q * 4];   // head block idx 992..1007
    hp4[q] = *(const float4v*)&pbS[992 + q * 4];
    hd4[q] = *(const float4v*)&dnS[992 + q * 4];
    c4[q] = *(const float4v*)&lrow[976 + q * 4];   // window m=61 (idx 976..991)
    p4[q] = *(const float4v*)&pbS[976 + q * 4];
    d4[q] = *(const float4v*)&dnS[976 + q * 4];
  }
  // head: t=998..991, idx=t+1=999..992, elem = idx-992 = 7-j
#pragma unroll
  for (int j = 0; j < 8; ++j) {
    int e = 7 - j;
    STEPB(998 - j, h4[e >> 2][e & 3], hp4[e >> 2][e & 3], hd4[e >> 2][e & 3]);
  }
  // main windows m=61..1: t = 16m+14 .. 16m-1 (desc), idx = 16m+15-j
  for (int m = 61; m >= 1; --m) {
    float4v n4[4], np4[4], nd4[4];
    int nb = (m > 1) ? (m - 1) * 16 : 0;   // m=1 prefetches tail block 0
#pragma unroll
    for (int q = 0; q < 4; ++q) {
      n4[q] = *(const float4v*)&lrow[nb + q * 4];
      np4[q] = *(const float4v*)&pbS[nb + q * 4];
      nd4[q] = *(const float4v*)&dnS[nb + q * 4];
    }
#pragma unroll
    for (int j = 0; j < 16; ++j) {
      int e = 15 - j;
      STEPB(16 * m + 14 - j, c4[e >> 2][e & 3], p4[e >> 2][e & 3], d4[e >> 2][e & 3]);
    }
#pragma unroll
    for (int q = 0; q < 4; ++q) { c4[q] = n4[q]; p4[q] = np4[q]; d4[q] = nd4[q]; }
  }
  // tail: t=14..0, idx=15..1, elem = 15-j (block 0 in c4)
#pragma unroll
  for (int j = 0; j < 15; ++j) {
    int e = 15 - j;
    STEPB(14 - j, c4[e >> 2][e & 3], p4[e >> 2][e & 3], d4[e >> 2][e & 3]);
  }
#undef STEPB
}

// ---- kernel 6: loss. alpha re-normalized per-t (Dpre prefix from dnm). ----
__global__ __launch_bounds__(512) void k_loss(const float* __restrict__ aod,
                                              const float* __restrict__ bp,
                                              const float* __restrict__ dnm,
                                              const int* __restrict__ hlens,
                                              float* __restrict__ out) {
  __shared__ float denL[NT];
  __shared__ float Dpre[NT];
  __shared__ float choff[64];
  __shared__ float ms[8][64], ss[8][64];
  int b = blockIdx.x, tid = threadIdx.x;
  for (int t = tid; t < NT; t += 512) denL[t] = dnm[b * NT + t];
  __syncthreads();
  if (tid < 64) {
    float s = 0.f;
#pragma unroll
    for (int i = 0; i < 16; ++i) { int t = tid * 16 + i; if (t < NT) s += denL[t]; }
    float v = s;
#pragma unroll
    for (int d = 1; d < 64; d <<= 1) { float u = __shfl_up(v, d); if (tid >= d) v += u; }
    choff[tid] = v - s;
  }
  __syncthreads();
  for (int t = tid; t < NT; t += 512) {
    float s = choff[t >> 4];
    int base = t & ~15;
    for (int i = base; i <= t; ++i) s += denL[i];
    Dpre[t] = s;   // inclusive prefix D(t)
  }
  __syncthreads();
  int w = tid >> 6, l = tid & 63;
  const float* ab = aod + (size_t)b * NT * NU;
  const float* pbp = bp + (size_t)b * NT * NU;
  float m = NEGINF, s = 0.f;
  int t0 = w * 125, t1 = t0 + 125;
  for (int t = t0; t < t1; ++t) {
    float av = ab[t * NU + l];          // alpha_ll (base-2)
    float pv = pbp[t * NU + l];         // bp normalized (base-2)
    float x = av - Dpre[t] * LOG2E + pv;
    if (__builtin_isnan(x) || x < -1.0e29f) continue;
    if (x > m) { s = s * fexp2(m - x) + 1.0f; m = x; }
    else       { s += fexp2(x - m); }
  }
  ms[w][l] = m; ss[w][l] = s;
  __syncthreads();
  if (w == 0) {
    float mm = NEGINF;
#pragma unroll
    for (int i = 0; i < 8; ++i) mm = fmaxf(mm, ms[i][l]);
    float lu;
    if (mm == NEGINF) lu = NEGINF;
    else {
      float st = 0.f;
#pragma unroll
      for (int i = 0; i < 8; ++i)
        st += (ms[i][l] == NEGINF) ? 0.f : ss[i][l] * fexp2(ms[i][l] - mm);
      lu = (mm + flog2(st)) * LN2F;
    }
    bool msk = __builtin_isinf(lu);
    float sv = msk ? 0.f : lu;
    float cv = msk ? 0.f : 1.f;
#pragma unroll
    for (int d = 1; d < 64; d <<= 1) { sv += __shfl_xor(sv, d); cv += __shfl_xor(cv, d); }
    if (l == 0) {
      float lf = sv / cv;
      if (hlens[b] < NU) lf = 0.f;
      atomicAdd(out, -lf * (1.0f / NB));
    }
  }
}

// ---------------------------------------------------------------------------
extern "C" void kernel_launch(void* const* d_in, const int* in_sizes, int n_in,
                              void* d_out, int out_size, void* d_ws, size_t ws_size,
                              hipStream_t stream) {
  const float* hs    = (const float*)d_in[0];
  const int*   hlens = (const int*)d_in[1];
  const int*   ys    = (const int*)d_in[2];
  const float* W     = (const float*)d_in[4];
  const float* bias  = (const float*)d_in[5];
  float* out = (float*)d_out;

  char* ws = (char*)d_ws;
  short* hsb   = (short*)(ws + 0);           // 16,384,000 B  live thru k_big
  short* WT    = (short*)(ws + 16384000);    //  5,242,880 B  live thru k_big
  short* WTlo  = (short*)(ws + 21626880);    //  5,242,880 B  dead after k_labg
  float* aod   = (float*)(ws + 21626880);    //  4,096,000 B  aliases WTlo (k_big writes)
  float* ll    = (float*)(ws + 26869760);    //  4,224,000 B
  float* L     = (float*)(ws + 31093760);    //  2,560,000 B
  float* dnm   = (float*)(ws + 33653760);    //     64,000 B
  float* bpb   = (float*)(ws + 33717760);    //  4,096,000 B  (end 37,813,760)

  k_cvt<<<4640, 256, 0, stream>>>(hs, W, hsb, WT, WTlo, out);
  k_labg<<<dim3(8, 16), 256, 0, stream>>>(hsb, WT, WTlo, ys, bias, ll);
  k_big<<<5016, 256, 0, stream>>>(hsb, WT, bias, ll, ys, L, aod);
  k_dred<<<63, 256, 0, stream>>>(L, dnm);
  k_bwd<<<16, 64, 0, stream>>>(ll, dnm, ys, bpb);
  k_loss<<<16, 512, 0, stream>>>(aod, bpb, dnm, hlens, out);
}